// Round 1
// baseline (803.490 us; speedup 1.0000x reference)
//
#include <hip/hip_runtime.h>
#include <hip/hip_bf16.h>
#include <stdint.h>

#define TT 2048
#define DD 1024
#define NE 8
#define FR 1408
#define FS 2816
#define RSCALE 2.5f

typedef __attribute__((ext_vector_type(8))) short bf16x8;
typedef __attribute__((ext_vector_type(4))) float f32x4;

__device__ __forceinline__ short f2bf(float f) {
  uint32_t u = __builtin_bit_cast(uint32_t, f);
  u = (u + 0x7fffu + ((u >> 16) & 1u)) >> 16;
  return (short)(uint16_t)u;
}

// ---------------- cast fp32 -> bf16 (x only) ----------------
__global__ void cast_kernel(const float* __restrict__ in, short* __restrict__ out, int n) {
  int i = (blockIdx.x * blockDim.x + threadIdx.x) * 4;
  if (i >= n) return;
  float4 v = *(const float4*)(in + i);
  short4 o;
  o.x = f2bf(v.x); o.y = f2bf(v.y); o.z = f2bf(v.z); o.w = f2bf(v.w);
  *(short4*)(out + i) = o;
}

// ---------------- gating: softmax over 8, top-2, normalize, scale ----------------
__global__ void gate_kernel(const float* __restrict__ x, const float* __restrict__ gw,
                            float* __restrict__ comb) {
  int t = blockIdx.x;
  int lane = threadIdx.x;  // 64 threads
  const float* xr = x + (size_t)t * DD + lane * 16;
  float4 xv[4];
#pragma unroll
  for (int i = 0; i < 4; ++i) xv[i] = *(const float4*)(xr + i * 4);
  float p[NE];
#pragma unroll
  for (int e = 0; e < NE; ++e) {
    const float* gr = gw + (size_t)e * DD + lane * 16;
    float s = 0.f;
#pragma unroll
    for (int i = 0; i < 4; ++i) {
      float4 g = *(const float4*)(gr + i * 4);
      s += xv[i].x * g.x + xv[i].y * g.y + xv[i].z * g.z + xv[i].w * g.w;
    }
    p[e] = s;
  }
#pragma unroll
  for (int off = 32; off >= 1; off >>= 1) {
#pragma unroll
    for (int e = 0; e < NE; ++e) p[e] += __shfl_xor(p[e], off);
  }
  // softmax (accurate expf: routing decisions must match fp32 reference)
  float mx = p[0];
#pragma unroll
  for (int e = 1; e < NE; ++e) mx = fmaxf(mx, p[e]);
  float s = 0.f, sc[NE];
#pragma unroll
  for (int e = 0; e < NE; ++e) { sc[e] = expf(p[e] - mx); s += sc[e]; }
  float inv = 1.f / s;
#pragma unroll
  for (int e = 0; e < NE; ++e) sc[e] *= inv;
  // greedy top-2, first-index tie-break (matches lax.top_k)
  int e1 = 0;
#pragma unroll
  for (int e = 1; e < NE; ++e) if (sc[e] > sc[e1]) e1 = e;
  int e2 = (e1 == 0) ? 1 : 0;
#pragma unroll
  for (int e = 0; e < NE; ++e) if (e != e1 && sc[e] > sc[e2]) e2 = e;
  float w1 = sc[e1], w2 = sc[e2];
  float k = RSCALE / (w1 + w2 + 1e-20f);
  if (lane < NE)
    comb[(size_t)t * NE + lane] = (lane == e1) ? w1 * k : ((lane == e2) ? w2 * k : 0.f);
}

// ---------------- GEMM: 128x128 tile, BK=32, 4 waves (2x2), 16x16x32 bf16 MFMA ----------------
// MODE 0: C0 = A@B0, C1 = A@B1, H = silu(C0)*C1 -> bf16
// MODE 1: O = A@B0                  (write, fp32)
// MODE 2: O += comb[row,z] * (A@B0) (atomicAdd, skip comb==0)
template <int MODE>
__global__ void __launch_bounds__(256) moe_gemm(
    const short* __restrict__ Ab, int lda, int64_t zA,
    const float* __restrict__ B0b, const float* __restrict__ B1b, int ldb, int64_t zB,
    int K,
    short* __restrict__ Hb, int ldh, int64_t zH,
    float* __restrict__ Ob,
    const float* __restrict__ comb) {
  const int z = blockIdx.z;
  const short* A = Ab + (int64_t)z * zA;
  const float* B0 = B0b + (int64_t)z * zB;
  const float* B1 = (MODE == 0) ? (B1b + (int64_t)z * zB) : nullptr;
  const int brow = blockIdx.y * 128;
  const int bcol = blockIdx.x * 128;

  __shared__ __align__(16) short lA[128 * 32];                       // [row][k]
  __shared__ __align__(16) short lB0[128 * 32];                      // [n][k] (transposed)
  __shared__ __align__(16) short lB1[(MODE == 0) ? 128 * 32 : 8];
  __shared__ float lComb[128];

  const int tid = threadIdx.x;
  const int lane = tid & 63;
  const int wave = tid >> 6;
  const int wr = wave >> 1, wc = wave & 1;

  if (MODE == 2 && tid < 128) lComb[tid] = comb[(int64_t)(brow + tid) * NE + z];

  f32x4 acc0[4][4];
  f32x4 acc1[(MODE == 0) ? 4 : 1][(MODE == 0) ? 4 : 1];
#pragma unroll
  for (int m = 0; m < 4; ++m)
#pragma unroll
    for (int n = 0; n < 4; ++n) {
      acc0[m][n] = (f32x4){0.f, 0.f, 0.f, 0.f};
      if constexpr (MODE == 0) acc1[m][n] = (f32x4){0.f, 0.f, 0.f, 0.f};
    }

  const int ar = tid >> 1;        // A row 0..127 (2 threads/row)
  const int ac = (tid & 1) * 16;  // A col offset in shorts
  const int bn = tid & 127;       // B tile col
  const int bk = (tid >> 7) * 16; // B k-half

  for (int k0 = 0; k0 < K; k0 += 32) {
    // stage A (bf16, row-major, K-contiguous)
    {
      const short* ag = A + (int64_t)(brow + ar) * lda + k0 + ac;
      bf16x8 v0 = *(const bf16x8*)ag;
      bf16x8 v1 = *(const bf16x8*)(ag + 8);
      *(bf16x8*)&lA[ar * 32 + ac] = v0;
      *(bf16x8*)&lA[ar * 32 + ac + 8] = v1;
    }
    // stage B0: fp32 row-major [k][n] -> bf16 LDS [n][k]
    {
      const float* bp = B0 + (int64_t)(k0 + bk) * ldb + bcol + bn;
      short sv[16];
#pragma unroll
      for (int i = 0; i < 16; ++i) sv[i] = f2bf(bp[(int64_t)i * ldb]);
      *(bf16x8*)&lB0[bn * 32 + bk] = *(bf16x8*)&sv[0];
      *(bf16x8*)&lB0[bn * 32 + bk + 8] = *(bf16x8*)&sv[8];
    }
    if constexpr (MODE == 0) {
      const float* bp = B1 + (int64_t)(k0 + bk) * ldb + bcol + bn;
      short sv[16];
#pragma unroll
      for (int i = 0; i < 16; ++i) sv[i] = f2bf(bp[(int64_t)i * ldb]);
      *(bf16x8*)&lB1[bn * 32 + bk] = *(bf16x8*)&sv[0];
      *(bf16x8*)&lB1[bn * 32 + bk + 8] = *(bf16x8*)&sv[8];
    }
    __syncthreads();
#pragma unroll
    for (int m = 0; m < 4; ++m) {
      bf16x8 af = *(const bf16x8*)&lA[(wr * 64 + m * 16 + (lane & 15)) * 32 + (lane >> 4) * 8];
#pragma unroll
      for (int n = 0; n < 4; ++n) {
        bf16x8 b0 = *(const bf16x8*)&lB0[(wc * 64 + n * 16 + (lane & 15)) * 32 + (lane >> 4) * 8];
        acc0[m][n] = __builtin_amdgcn_mfma_f32_16x16x32_bf16(af, b0, acc0[m][n], 0, 0, 0);
        if constexpr (MODE == 0) {
          bf16x8 b1 = *(const bf16x8*)&lB1[(wc * 64 + n * 16 + (lane & 15)) * 32 + (lane >> 4) * 8];
          acc1[m][n] = __builtin_amdgcn_mfma_f32_16x16x32_bf16(af, b1, acc1[m][n], 0, 0, 0);
        }
      }
    }
    __syncthreads();
  }

  // epilogue: D[row] = (lane>>4)*4+r, D[col] = lane&15 (m89-verified layout)
#pragma unroll
  for (int m = 0; m < 4; ++m) {
#pragma unroll
    for (int n = 0; n < 4; ++n) {
#pragma unroll
      for (int r = 0; r < 4; ++r) {
        int rl = wr * 64 + m * 16 + (lane >> 4) * 4 + r;
        int cl = wc * 64 + n * 16 + (lane & 15);
        int row = brow + rl;
        int col = bcol + cl;
        float g = acc0[m][n][r];
        if constexpr (MODE == 0) {
          float u = acc1[m][n][r];
          float h = g / (1.f + __expf(-g)) * u;  // silu(g)*u
          Hb[(int64_t)z * zH + (int64_t)row * ldh + col] = f2bf(h);
        } else if constexpr (MODE == 1) {
          Ob[(int64_t)row * DD + col] = g;
        } else {
          float cw = lComb[rl];
          if (cw != 0.f) atomicAdd(&Ob[(int64_t)row * DD + col], cw * g);
        }
      }
    }
  }
}

extern "C" void kernel_launch(void* const* d_in, const int* in_sizes, int n_in,
                              void* d_out, int out_size, void* d_ws, size_t ws_size,
                              hipStream_t stream) {
  const float* x       = (const float*)d_in[0];
  const float* gw      = (const float*)d_in[1];
  const float* w_gate  = (const float*)d_in[2];
  const float* w_up    = (const float*)d_in[3];
  const float* w_down  = (const float*)d_in[4];
  const float* sw_gate = (const float*)d_in[5];
  const float* sw_up   = (const float*)d_in[6];
  const float* sw_down = (const float*)d_in[7];
  float* out = (float*)d_out;

  char* ws = (char*)d_ws;
  float* comb = (float*)ws;              ws += 256 * 1024;                 // 64KB used
  short* Xb   = (short*)ws;              ws += (size_t)TT * DD * 2;        // 4MB
  short* Hs   = (short*)ws;              ws += (size_t)TT * FS * 2;        // 11.5MB
  short* Hr   = (short*)ws;              /* 8*TT*FR*2 = 46MB */

  // 1. cast x -> bf16
  cast_kernel<<<dim3((TT * DD) / 1024), dim3(256), 0, stream>>>(x, Xb, TT * DD);
  // 2. gating (fp32 exact)
  gate_kernel<<<dim3(TT), dim3(64), 0, stream>>>(x, gw, comb);
  // 3. shared gate/up -> Hs
  moe_gemm<0><<<dim3(FS / 128, TT / 128, 1), dim3(256), 0, stream>>>(
      Xb, DD, 0, sw_gate, sw_up, FS, 0, DD, Hs, FS, 0, nullptr, nullptr);
  // 4. routed gate/up (all experts) -> Hr
  moe_gemm<0><<<dim3(FR / 128, TT / 128, NE), dim3(256), 0, stream>>>(
      Xb, DD, 0, w_gate, w_up, FR, (int64_t)DD * FR, DD, Hr, FR, (int64_t)TT * FR, nullptr, nullptr);
  // 5. shared down: out = Hs @ sw_down   (initializes all of out)
  moe_gemm<1><<<dim3(DD / 128, TT / 128, 1), dim3(256), 0, stream>>>(
      Hs, FS, 0, sw_down, nullptr, DD, 0, FS, nullptr, 0, 0, out, nullptr);
  // 6. routed down: out += combine * (Hr @ w_down)   (atomicAdd)
  moe_gemm<2><<<dim3(DD / 128, TT / 128, NE), dim3(256), 0, stream>>>(
      Hr, FR, (int64_t)TT * FR, w_down, nullptr, DD, (int64_t)FR * DD, FR, nullptr, 0, 0, out, comb);
}

// Round 3
// 686.452 us; speedup vs baseline: 1.1705x; 1.1705x over previous
//
#include <hip/hip_runtime.h>
#include <hip/hip_bf16.h>
#include <stdint.h>

#define TT 2048
#define DD 1024
#define NE 8
#define FR 1408
#define FS 2816
#define RSCALE 2.5f

typedef __attribute__((ext_vector_type(8))) short bf16x8;
typedef __attribute__((ext_vector_type(4))) float f32x4;

__device__ __forceinline__ short f2bf(float f) {
  uint32_t u = __builtin_bit_cast(uint32_t, f);
  u = (u + 0x7fffu + ((u >> 16) & 1u)) >> 16;
  return (short)(uint16_t)u;
}

// ---------------- cast fp32 -> bf16 (x only) ----------------
__global__ void cast_kernel(const float* __restrict__ in, short* __restrict__ out, int n) {
  int i = (blockIdx.x * blockDim.x + threadIdx.x) * 4;
  if (i >= n) return;
  float4 v = *(const float4*)(in + i);
  short4 o;
  o.x = f2bf(v.x); o.y = f2bf(v.y); o.z = f2bf(v.z); o.w = f2bf(v.w);
  *(short4*)(out + i) = o;
}

// ---------------- transpose + cast: fp32 [K][N] -> bf16 [N][K] ----------------
__global__ void __launch_bounds__(256) tcast_kernel(const float* __restrict__ in,
                                                    short* __restrict__ out,
                                                    int K, int N, int64_t zin, int64_t zout) {
  const int z = blockIdx.z;
  in += (int64_t)z * zin;
  out += (int64_t)z * zout;
  __shared__ float tile[32][33];
  const int k0 = blockIdx.y * 32, n0 = blockIdx.x * 32;
  const int tx = threadIdx.x, ty = threadIdx.y;  // (32, 8)
#pragma unroll
  for (int i = 0; i < 4; ++i)
    tile[ty * 4 + i][tx] = in[(int64_t)(k0 + ty * 4 + i) * N + n0 + tx];
  __syncthreads();
#pragma unroll
  for (int i = 0; i < 4; ++i)
    out[(int64_t)(n0 + ty * 4 + i) * K + k0 + tx] = f2bf(tile[tx][ty * 4 + i]);
}

// ---------------- gating: softmax over 8, top-2, normalize, scale ----------------
__global__ void gate_kernel(const float* __restrict__ x, const float* __restrict__ gw,
                            float* __restrict__ comb) {
  int t = blockIdx.x;
  int lane = threadIdx.x;  // 64 threads
  const float* xr = x + (size_t)t * DD + lane * 16;
  float4 xv[4];
#pragma unroll
  for (int i = 0; i < 4; ++i) xv[i] = *(const float4*)(xr + i * 4);
  float p[NE];
#pragma unroll
  for (int e = 0; e < NE; ++e) {
    const float* gr = gw + (size_t)e * DD + lane * 16;
    float s = 0.f;
#pragma unroll
    for (int i = 0; i < 4; ++i) {
      float4 g = *(const float4*)(gr + i * 4);
      s += xv[i].x * g.x + xv[i].y * g.y + xv[i].z * g.z + xv[i].w * g.w;
    }
    p[e] = s;
  }
#pragma unroll
  for (int off = 32; off >= 1; off >>= 1) {
#pragma unroll
    for (int e = 0; e < NE; ++e) p[e] += __shfl_xor(p[e], off);
  }
  float mx = p[0];
#pragma unroll
  for (int e = 1; e < NE; ++e) mx = fmaxf(mx, p[e]);
  float s = 0.f, sc[NE];
#pragma unroll
  for (int e = 0; e < NE; ++e) { sc[e] = expf(p[e] - mx); s += sc[e]; }
  float inv = 1.f / s;
#pragma unroll
  for (int e = 0; e < NE; ++e) sc[e] *= inv;
  int e1 = 0;
#pragma unroll
  for (int e = 1; e < NE; ++e) if (sc[e] > sc[e1]) e1 = e;
  int e2 = (e1 == 0) ? 1 : 0;
#pragma unroll
  for (int e = 0; e < NE; ++e) if (e != e1 && sc[e] > sc[e2]) e2 = e;
  float w1 = sc[e1], w2 = sc[e2];
  float k = RSCALE / (w1 + w2 + 1e-20f);
  if (lane < NE)
    comb[(size_t)t * NE + lane] = (lane == e1) ? w1 * k : ((lane == e2) ? w2 * k : 0.f);
}

// ---- stage a 128x32 bf16 tile (row-major, ld elems) into linear LDS [128][32] ----
// 8192 B = 512 x 16B chunks; 256 threads x 2 iters; dest = wave-uniform base + lane*16.
__device__ __forceinline__ void stage32(const short* __restrict__ g, int64_t ld,
                                        short* l, int wave, int lane) {
#pragma unroll
  for (int i = 0; i < 2; ++i) {
    int c = i * 256 + wave * 64 + lane;
    __builtin_amdgcn_global_load_lds(
        (const __attribute__((address_space(1))) void*)(g + (int64_t)(c >> 2) * ld + (c & 3) * 8),
        (__attribute__((address_space(3))) void*)(l + (i * 256 + wave * 64) * 8),
        16, 0, 0);
  }
}

// ---------------- GEMM: 128x128 tile, BK=32, 4 waves (2x2), 16x16x32 bf16 MFMA ----
// A bf16 [M][K]; B bf16 [N][K] (pre-transposed). m97 structure: global_load_lds staging.
// MODE 0: H = silu(A@B0^T)*(A@B1^T) -> bf16
// MODE 1: O = A@B0^T                 (write, fp32)
// MODE 2: O += comb[row,z]*(A@B0^T)  (atomicAdd, skip comb==0)
template <int MODE>
__global__ void __launch_bounds__(256) moe_gemm(
    const short* __restrict__ Ab, int lda, int64_t zA,
    const short* __restrict__ B0b, const short* __restrict__ B1b, int ldb, int64_t zB,
    int K,
    short* __restrict__ Hb, int ldh, int64_t zH,
    float* __restrict__ Ob,
    const float* __restrict__ comb) {
  const int z = blockIdx.z;
  const short* A = Ab + (int64_t)z * zA;
  const short* B0 = B0b + (int64_t)z * zB;
  const short* B1 = (MODE == 0) ? (B1b + (int64_t)z * zB) : nullptr;
  const int brow = blockIdx.y * 128;
  const int bcol = blockIdx.x * 128;

  __shared__ __align__(16) short lA[128 * 32];
  __shared__ __align__(16) short lB0[128 * 32];
  __shared__ __align__(16) short lB1[(MODE == 0) ? 128 * 32 : 8];
  __shared__ float lComb[128];

  const int tid = threadIdx.x;
  const int lane = tid & 63;
  const int wave = tid >> 6;
  const int wr = wave >> 1, wc = wave & 1;

  if (MODE == 2 && tid < 128) lComb[tid] = comb[(int64_t)(brow + tid) * NE + z];

  f32x4 acc0[4][4];
  f32x4 acc1[(MODE == 0) ? 4 : 1][(MODE == 0) ? 4 : 1];
#pragma unroll
  for (int m = 0; m < 4; ++m)
#pragma unroll
    for (int n = 0; n < 4; ++n) {
      acc0[m][n] = (f32x4){0.f, 0.f, 0.f, 0.f};
      if constexpr (MODE == 0) acc1[m][n] = (f32x4){0.f, 0.f, 0.f, 0.f};
    }

  const short* Abase = A + (int64_t)brow * lda;
  const short* B0base = B0 + (int64_t)bcol * ldb;
  const short* B1base = (MODE == 0) ? (B1 + (int64_t)bcol * ldb) : nullptr;

  for (int k0 = 0; k0 < K; k0 += 32) {
    stage32(Abase + k0, lda, lA, wave, lane);
    stage32(B0base + k0, ldb, lB0, wave, lane);
    if constexpr (MODE == 0) stage32(B1base + k0, ldb, lB1, wave, lane);
    __syncthreads();
#pragma unroll
    for (int m = 0; m < 4; ++m) {
      bf16x8 af = *(const bf16x8*)&lA[(wr * 64 + m * 16 + (lane & 15)) * 32 + (lane >> 4) * 8];
#pragma unroll
      for (int n = 0; n < 4; ++n) {
        bf16x8 b0 = *(const bf16x8*)&lB0[(wc * 64 + n * 16 + (lane & 15)) * 32 + (lane >> 4) * 8];
        acc0[m][n] = __builtin_amdgcn_mfma_f32_16x16x32_bf16(af, b0, acc0[m][n], 0, 0, 0);
        if constexpr (MODE == 0) {
          bf16x8 b1 = *(const bf16x8*)&lB1[(wc * 64 + n * 16 + (lane & 15)) * 32 + (lane >> 4) * 8];
          acc1[m][n] = __builtin_amdgcn_mfma_f32_16x16x32_bf16(af, b1, acc1[m][n], 0, 0, 0);
        }
      }
    }
    __syncthreads();
  }

  // epilogue: D[row] = (lane>>4)*4+r, D[col] = lane&15 (m89-verified layout)
#pragma unroll
  for (int m = 0; m < 4; ++m) {
#pragma unroll
    for (int n = 0; n < 4; ++n) {
#pragma unroll
      for (int r = 0; r < 4; ++r) {
        int rl = wr * 64 + m * 16 + (lane >> 4) * 4 + r;
        int cl = wc * 64 + n * 16 + (lane & 15);
        int row = brow + rl;
        int col = bcol + cl;
        float g = acc0[m][n][r];
        if constexpr (MODE == 0) {
          float u = acc1[m][n][r];
          float h = g / (1.f + __expf(-g)) * u;  // silu(g)*u
          Hb[(int64_t)z * zH + (int64_t)row * ldh + col] = f2bf(h);
        } else if constexpr (MODE == 1) {
          Ob[(int64_t)row * DD + col] = g;
        } else {
          float cw = lComb[rl];
          if (cw != 0.f) atomicAdd(&Ob[(int64_t)row * DD + col], cw * g);
        }
      }
    }
  }
}

extern "C" void kernel_launch(void* const* d_in, const int* in_sizes, int n_in,
                              void* d_out, int out_size, void* d_ws, size_t ws_size,
                              hipStream_t stream) {
  const float* x       = (const float*)d_in[0];
  const float* gw      = (const float*)d_in[1];
  const float* w_gate  = (const float*)d_in[2];
  const float* w_up    = (const float*)d_in[3];
  const float* w_down  = (const float*)d_in[4];
  const float* sw_gate = (const float*)d_in[5];
  const float* sw_up   = (const float*)d_in[6];
  const float* sw_down = (const float*)d_in[7];
  float* out = (float*)d_out;

  char* ws = (char*)d_ws;
  float* comb = (float*)ws;  ws += 256 * 1024;
  short* Xb   = (short*)ws;  ws += (size_t)TT * DD * 2;            // 4 MB
  short* Hs   = (short*)ws;  ws += (size_t)TT * FS * 2;            // 11.5 MB
  short* Hr   = (short*)ws;  ws += (size_t)NE * TT * FR * 2;       // 46 MB
  short* wgT  = (short*)ws;  ws += (size_t)NE * FR * DD * 2;       // 23 MB  [E][F][D]
  short* wuT  = (short*)ws;  ws += (size_t)NE * FR * DD * 2;       // 23 MB
  short* wdT  = (short*)ws;  ws += (size_t)NE * DD * FR * 2;       // 23 MB  [E][D][F]
  short* swgT = (short*)ws;  ws += (size_t)FS * DD * 2;            // 5.8 MB [FS][D]
  short* swuT = (short*)ws;  ws += (size_t)FS * DD * 2;            // 5.8 MB
  short* swdT = (short*)ws;  /* [D][FS] 5.8 MB */                  // total ~148 MB

  // 1. cast x -> bf16
  cast_kernel<<<dim3((TT * DD) / 1024), dim3(256), 0, stream>>>(x, Xb, TT * DD);
  // 2. gating (fp32 exact)
  gate_kernel<<<dim3(TT), dim3(64), 0, stream>>>(x, gw, comb);
  // 3. one-time weight transpose+cast to bf16 [N][K]
  dim3 tb(32, 8);
  tcast_kernel<<<dim3(FR / 32, DD / 32, NE), tb, 0, stream>>>(w_gate, wgT, DD, FR, (int64_t)DD * FR, (int64_t)FR * DD);
  tcast_kernel<<<dim3(FR / 32, DD / 32, NE), tb, 0, stream>>>(w_up,   wuT, DD, FR, (int64_t)DD * FR, (int64_t)FR * DD);
  tcast_kernel<<<dim3(DD / 32, FR / 32, NE), tb, 0, stream>>>(w_down, wdT, FR, DD, (int64_t)FR * DD, (int64_t)DD * FR);
  tcast_kernel<<<dim3(FS / 32, DD / 32, 1),  tb, 0, stream>>>(sw_gate, swgT, DD, FS, 0, 0);
  tcast_kernel<<<dim3(FS / 32, DD / 32, 1),  tb, 0, stream>>>(sw_up,   swuT, DD, FS, 0, 0);
  tcast_kernel<<<dim3(DD / 32, FS / 32, 1),  tb, 0, stream>>>(sw_down, swdT, FS, DD, 0, 0);
  // 4. shared gate/up -> Hs
  moe_gemm<0><<<dim3(FS / 128, TT / 128, 1), dim3(256), 0, stream>>>(
      Xb, DD, 0, swgT, swuT, DD, 0, DD, Hs, FS, 0, nullptr, nullptr);
  // 5. routed gate/up (all experts) -> Hr
  moe_gemm<0><<<dim3(FR / 128, TT / 128, NE), dim3(256), 0, stream>>>(
      Xb, DD, 0, wgT, wuT, DD, (int64_t)FR * DD, DD, Hr, FR, (int64_t)TT * FR, nullptr, nullptr);
  // 6. shared down: out = Hs @ swdT^T (initializes all of out)
  moe_gemm<1><<<dim3(DD / 128, TT / 128, 1), dim3(256), 0, stream>>>(
      Hs, FS, 0, swdT, nullptr, FS, 0, FS, nullptr, 0, 0, out, nullptr);
  // 7. routed down: out += combine * (Hr @ wdT^T) (atomicAdd)
  moe_gemm<2><<<dim3(DD / 128, TT / 128, NE), dim3(256), 0, stream>>>(
      Hr, FR, (int64_t)TT * FR, wdT, nullptr, FR, (int64_t)DD * FR, FR, nullptr, 0, 0, out, comb);
}

// Round 4
// 499.898 us; speedup vs baseline: 1.6073x; 1.3732x over previous
//
#include <hip/hip_runtime.h>
#include <hip/hip_bf16.h>
#include <stdint.h>

#define TT 2048
#define DD 1024
#define NE 8
#define FR 1408
#define FS 2816
#define RSCALE 2.5f
#define NSLOT (TT * 2)

typedef __attribute__((ext_vector_type(8))) short bf16x8;
typedef __attribute__((ext_vector_type(4))) float f32x4;

__device__ __forceinline__ short f2bf(float f) {
  uint32_t u = __builtin_bit_cast(uint32_t, f);
  u = (u + 0x7fffu + ((u >> 16) & 1u)) >> 16;
  return (short)(uint16_t)u;
}

// ---------------- cast fp32 -> bf16 (x only) ----------------
__global__ void cast_kernel(const float* __restrict__ in, short* __restrict__ out, int n) {
  int i = (blockIdx.x * blockDim.x + threadIdx.x) * 4;
  if (i >= n) return;
  float4 v = *(const float4*)(in + i);
  short4 o;
  o.x = f2bf(v.x); o.y = f2bf(v.y); o.z = f2bf(v.z); o.w = f2bf(v.w);
  *(short4*)(out + i) = o;
}

// ---------------- transpose + cast: fp32 [K][N] -> bf16 [N][K] ----------------
__global__ void __launch_bounds__(256) tcast_kernel(const float* __restrict__ in,
                                                    short* __restrict__ out,
                                                    int K, int N, int64_t zin, int64_t zout) {
  const int z = blockIdx.z;
  in += (int64_t)z * zin;
  out += (int64_t)z * zout;
  __shared__ float tile[32][33];
  const int k0 = blockIdx.y * 32, n0 = blockIdx.x * 32;
  const int tx = threadIdx.x, ty = threadIdx.y;  // (32, 8)
#pragma unroll
  for (int i = 0; i < 4; ++i)
    tile[ty * 4 + i][tx] = in[(int64_t)(k0 + ty * 4 + i) * N + n0 + tx];
  __syncthreads();
#pragma unroll
  for (int i = 0; i < 4; ++i)
    out[(int64_t)(n0 + ty * 4 + i) * K + k0 + tx] = f2bf(tile[tx][ty * 4 + i]);
}

// ------------- gating: softmax over 8, top-2, normalize, scale -> (expert, weight) pairs -------------
__global__ void gate_kernel(const float* __restrict__ x, const float* __restrict__ gw,
                            int* __restrict__ te, float* __restrict__ tw) {
  int t = blockIdx.x;
  int lane = threadIdx.x;  // 64 threads
  const float* xr = x + (size_t)t * DD + lane * 16;
  float4 xv[4];
#pragma unroll
  for (int i = 0; i < 4; ++i) xv[i] = *(const float4*)(xr + i * 4);
  float p[NE];
#pragma unroll
  for (int e = 0; e < NE; ++e) {
    const float* gr = gw + (size_t)e * DD + lane * 16;
    float s = 0.f;
#pragma unroll
    for (int i = 0; i < 4; ++i) {
      float4 g = *(const float4*)(gr + i * 4);
      s += xv[i].x * g.x + xv[i].y * g.y + xv[i].z * g.z + xv[i].w * g.w;
    }
    p[e] = s;
  }
#pragma unroll
  for (int off = 32; off >= 1; off >>= 1) {
#pragma unroll
    for (int e = 0; e < NE; ++e) p[e] += __shfl_xor(p[e], off);
  }
  float mx = p[0];
#pragma unroll
  for (int e = 1; e < NE; ++e) mx = fmaxf(mx, p[e]);
  float s = 0.f, sc[NE];
#pragma unroll
  for (int e = 0; e < NE; ++e) { sc[e] = expf(p[e] - mx); s += sc[e]; }
  float inv = 1.f / s;
#pragma unroll
  for (int e = 0; e < NE; ++e) sc[e] *= inv;
  int e1 = 0;
#pragma unroll
  for (int e = 1; e < NE; ++e) if (sc[e] > sc[e1]) e1 = e;
  int e2 = (e1 == 0) ? 1 : 0;
#pragma unroll
  for (int e = 0; e < NE; ++e) if (e != e1 && sc[e] > sc[e2]) e2 = e;
  float w1 = sc[e1], w2 = sc[e2];
  float k = RSCALE / (w1 + w2 + 1e-20f);
  if (lane == 0) {
    te[t * 2] = e1;     tw[t * 2] = w1 * k;
    te[t * 2 + 1] = e2; tw[t * 2 + 1] = w2 * k;
  }
}

// ------------- build compact per-expert slot lists: cnt/off/eidx/wslot (1 block) -------------
__global__ void __launch_bounds__(1024) scatter_kernel(const int* __restrict__ te,
                                                       const float* __restrict__ tw,
                                                       int* __restrict__ cnt, int* __restrict__ off,
                                                       int* __restrict__ eidx, float* __restrict__ wslot) {
  __shared__ int lcnt[NE], loff[NE], lrun[NE];
  const int tid = threadIdx.x;
  if (tid < NE) lcnt[tid] = 0;
  __syncthreads();
  for (int s = tid; s < NSLOT; s += 1024) atomicAdd(&lcnt[te[s]], 1);
  __syncthreads();
  if (tid == 0) {
    int acc = 0;
    for (int e = 0; e < NE; ++e) { loff[e] = acc; lrun[e] = acc; acc += lcnt[e]; }
  }
  __syncthreads();
  for (int s = tid; s < NSLOT; s += 1024) {
    int e = te[s];
    int p = atomicAdd(&lrun[e], 1);
    eidx[p] = s >> 1;
    wslot[p] = tw[s];
  }
  if (tid < NE) { cnt[tid] = lcnt[tid]; off[tid] = loff[tid]; }
}

// ---- stage a 128x32 bf16 tile (row-major, ld elems) into linear LDS [128][32] ----
__device__ __forceinline__ void stage32(const short* __restrict__ g, int64_t ld,
                                        short* l, int wave, int lane) {
#pragma unroll
  for (int i = 0; i < 2; ++i) {
    int c = i * 256 + wave * 64 + lane;
    __builtin_amdgcn_global_load_lds(
        (const __attribute__((address_space(1))) void*)(g + (int64_t)(c >> 2) * ld + (c & 3) * 8),
        (__attribute__((address_space(3))) void*)(l + (i * 256 + wave * 64) * 8),
        16, 0, 0);
  }
}

// ---------------- dense GEMM (shared expert): 128x128, BK=32, 4 waves ----------------
// MODE 0: H = silu(A@B0^T)*(A@B1^T) -> bf16 ; MODE 1: O = A@B0^T (fp32 write)
template <int MODE>
__global__ void __launch_bounds__(256) moe_gemm(
    const short* __restrict__ Ab, int lda,
    const short* __restrict__ B0b, const short* __restrict__ B1b, int ldb,
    int K,
    short* __restrict__ Hb, int ldh,
    float* __restrict__ Ob) {
  const int brow = blockIdx.y * 128;
  const int bcol = blockIdx.x * 128;

  __shared__ __align__(16) short lA[128 * 32];
  __shared__ __align__(16) short lB0[128 * 32];
  __shared__ __align__(16) short lB1[(MODE == 0) ? 128 * 32 : 8];

  const int tid = threadIdx.x;
  const int lane = tid & 63;
  const int wave = tid >> 6;
  const int wr = wave >> 1, wc = wave & 1;

  f32x4 acc0[4][4];
  f32x4 acc1[(MODE == 0) ? 4 : 1][(MODE == 0) ? 4 : 1];
#pragma unroll
  for (int m = 0; m < 4; ++m)
#pragma unroll
    for (int n = 0; n < 4; ++n) {
      acc0[m][n] = (f32x4){0.f, 0.f, 0.f, 0.f};
      if constexpr (MODE == 0) acc1[m][n] = (f32x4){0.f, 0.f, 0.f, 0.f};
    }

  const short* Abase = Ab + (int64_t)brow * lda;
  const short* B0base = B0b + (int64_t)bcol * ldb;
  const short* B1base = (MODE == 0) ? (B1b + (int64_t)bcol * ldb) : nullptr;

  for (int k0 = 0; k0 < K; k0 += 32) {
    stage32(Abase + k0, lda, lA, wave, lane);
    stage32(B0base + k0, ldb, lB0, wave, lane);
    if constexpr (MODE == 0) stage32(B1base + k0, ldb, lB1, wave, lane);
    __syncthreads();
#pragma unroll
    for (int m = 0; m < 4; ++m) {
      bf16x8 af = *(const bf16x8*)&lA[(wr * 64 + m * 16 + (lane & 15)) * 32 + (lane >> 4) * 8];
#pragma unroll
      for (int n = 0; n < 4; ++n) {
        bf16x8 b0 = *(const bf16x8*)&lB0[(wc * 64 + n * 16 + (lane & 15)) * 32 + (lane >> 4) * 8];
        acc0[m][n] = __builtin_amdgcn_mfma_f32_16x16x32_bf16(af, b0, acc0[m][n], 0, 0, 0);
        if constexpr (MODE == 0) {
          bf16x8 b1 = *(const bf16x8*)&lB1[(wc * 64 + n * 16 + (lane & 15)) * 32 + (lane >> 4) * 8];
          acc1[m][n] = __builtin_amdgcn_mfma_f32_16x16x32_bf16(af, b1, acc1[m][n], 0, 0, 0);
        }
      }
    }
    __syncthreads();
  }

#pragma unroll
  for (int m = 0; m < 4; ++m)
#pragma unroll
    for (int n = 0; n < 4; ++n)
#pragma unroll
      for (int r = 0; r < 4; ++r) {
        int row = brow + wr * 64 + m * 16 + (lane >> 4) * 4 + r;
        int col = bcol + wc * 64 + n * 16 + (lane & 15);
        float g = acc0[m][n][r];
        if constexpr (MODE == 0) {
          float u = acc1[m][n][r];
          Hb[(int64_t)row * ldh + col] = f2bf(g / (1.f + __expf(-g)) * u);
        } else {
          Ob[(int64_t)row * DD + col] = g;
        }
      }
}

// ---------------- sparse GU: gathered A rows, compact H output ----------------
__global__ void __launch_bounds__(256) gu_sparse(
    const short* __restrict__ Xb,
    const short* __restrict__ wgT, const short* __restrict__ wuT,
    short* __restrict__ Hr,
    const int* __restrict__ cnt, const int* __restrict__ off,
    const int* __restrict__ eidx) {
  const int z = blockIdx.z;
  const int c = cnt[z];
  const int m0 = blockIdx.y * 128;        // chunk-local slot base
  if (m0 >= c) return;
  const int base = off[z];
  const int bcol = blockIdx.x * 128;

  __shared__ __align__(16) short lA[128 * 32];
  __shared__ __align__(16) short lB0[128 * 32];
  __shared__ __align__(16) short lB1[128 * 32];

  const int tid = threadIdx.x;
  const int lane = tid & 63;
  const int wave = tid >> 6;
  const int wr = wave >> 1, wc = wave & 1;

  // per-lane gathered A row pointers (2 chunks of 16B per lane)
  const short* aptr[2];
#pragma unroll
  for (int i = 0; i < 2; ++i) {
    int cl = i * 256 + wave * 64 + lane;
    int r = cl >> 2;                       // local row 0..127
    int sv = m0 + r; if (sv >= c) sv = c - 1;
    aptr[i] = Xb + (int64_t)eidx[base + sv] * DD + (cl & 3) * 8;
  }

  f32x4 acc0[4][4], acc1[4][4];
#pragma unroll
  for (int m = 0; m < 4; ++m)
#pragma unroll
    for (int n = 0; n < 4; ++n) {
      acc0[m][n] = (f32x4){0.f, 0.f, 0.f, 0.f};
      acc1[m][n] = (f32x4){0.f, 0.f, 0.f, 0.f};
    }

  const short* B0base = wgT + (int64_t)z * FR * DD + (int64_t)bcol * DD;
  const short* B1base = wuT + (int64_t)z * FR * DD + (int64_t)bcol * DD;

  for (int k0 = 0; k0 < DD; k0 += 32) {
#pragma unroll
    for (int i = 0; i < 2; ++i)
      __builtin_amdgcn_global_load_lds(
          (const __attribute__((address_space(1))) void*)(aptr[i] + k0),
          (__attribute__((address_space(3))) void*)(lA + (i * 256 + wave * 64) * 8),
          16, 0, 0);
    stage32(B0base + k0, DD, lB0, wave, lane);
    stage32(B1base + k0, DD, lB1, wave, lane);
    __syncthreads();
#pragma unroll
    for (int m = 0; m < 4; ++m) {
      bf16x8 af = *(const bf16x8*)&lA[(wr * 64 + m * 16 + (lane & 15)) * 32 + (lane >> 4) * 8];
#pragma unroll
      for (int n = 0; n < 4; ++n) {
        bf16x8 b0 = *(const bf16x8*)&lB0[(wc * 64 + n * 16 + (lane & 15)) * 32 + (lane >> 4) * 8];
        acc0[m][n] = __builtin_amdgcn_mfma_f32_16x16x32_bf16(af, b0, acc0[m][n], 0, 0, 0);
        bf16x8 b1 = *(const bf16x8*)&lB1[(wc * 64 + n * 16 + (lane & 15)) * 32 + (lane >> 4) * 8];
        acc1[m][n] = __builtin_amdgcn_mfma_f32_16x16x32_bf16(af, b1, acc1[m][n], 0, 0, 0);
      }
    }
    __syncthreads();
  }

#pragma unroll
  for (int m = 0; m < 4; ++m)
#pragma unroll
    for (int n = 0; n < 4; ++n)
#pragma unroll
      for (int r = 0; r < 4; ++r) {
        int rl = wr * 64 + m * 16 + (lane >> 4) * 4 + r;
        int sv = m0 + rl;
        if (sv < c) {
          int col = bcol + wc * 64 + n * 16 + (lane & 15);
          float g = acc0[m][n][r], u = acc1[m][n][r];
          Hr[(int64_t)(base + sv) * FR + col] = f2bf(g / (1.f + __expf(-g)) * u);
        }
      }
}

// ---------------- sparse down: compact A rows, scatter-add to out ----------------
__global__ void __launch_bounds__(256) down_sparse(
    const short* __restrict__ Hr,
    const short* __restrict__ wdT,
    float* __restrict__ out,
    const int* __restrict__ cnt, const int* __restrict__ off,
    const int* __restrict__ eidx, const float* __restrict__ wslot) {
  const int z = blockIdx.z;
  const int c = cnt[z];
  const int m0 = blockIdx.y * 128;
  if (m0 >= c) return;
  const int base = off[z];
  const int bcol = blockIdx.x * 128;

  __shared__ __align__(16) short lA[128 * 32];
  __shared__ __align__(16) short lB0[128 * 32];
  __shared__ int lTok[128];
  __shared__ float lW[128];

  const int tid = threadIdx.x;
  const int lane = tid & 63;
  const int wave = tid >> 6;
  const int wr = wave >> 1, wc = wave & 1;

  if (tid < 128) {
    int sv = m0 + tid;
    if (sv < c) { lTok[tid] = eidx[base + sv]; lW[tid] = wslot[base + sv]; }
    else lW[tid] = 0.f;
  }

  f32x4 acc0[4][4];
#pragma unroll
  for (int m = 0; m < 4; ++m)
#pragma unroll
    for (int n = 0; n < 4; ++n) acc0[m][n] = (f32x4){0.f, 0.f, 0.f, 0.f};

  // clamp whole-chunk tail rows onto row (c-1) to avoid reading past the compact region
  const int64_t arow0 = base + m0;
  const short* B0base = wdT + (int64_t)z * DD * FR + (int64_t)bcol * FR;

  for (int k0 = 0; k0 < FR; k0 += 32) {
#pragma unroll
    for (int i = 0; i < 2; ++i) {
      int cl = i * 256 + wave * 64 + lane;
      int r = cl >> 2;
      int sv = m0 + r; if (sv >= c) sv = c - 1;
      __builtin_amdgcn_global_load_lds(
          (const __attribute__((address_space(1))) void*)(Hr + (int64_t)(base + sv) * FR + k0 + (cl & 3) * 8),
          (__attribute__((address_space(3))) void*)(lA + (i * 256 + wave * 64) * 8),
          16, 0, 0);
    }
    stage32(B0base + k0, FR, lB0, wave, lane);
    __syncthreads();
#pragma unroll
    for (int m = 0; m < 4; ++m) {
      bf16x8 af = *(const bf16x8*)&lA[(wr * 64 + m * 16 + (lane & 15)) * 32 + (lane >> 4) * 8];
#pragma unroll
      for (int n = 0; n < 4; ++n) {
        bf16x8 b0 = *(const bf16x8*)&lB0[(wc * 64 + n * 16 + (lane & 15)) * 32 + (lane >> 4) * 8];
        acc0[m][n] = __builtin_amdgcn_mfma_f32_16x16x32_bf16(af, b0, acc0[m][n], 0, 0, 0);
      }
    }
    __syncthreads();
  }

#pragma unroll
  for (int m = 0; m < 4; ++m)
#pragma unroll
    for (int n = 0; n < 4; ++n)
#pragma unroll
      for (int r = 0; r < 4; ++r) {
        int rl = wr * 64 + m * 16 + (lane >> 4) * 4 + r;
        if (m0 + rl < c) {
          int col = bcol + wc * 64 + n * 16 + (lane & 15);
          atomicAdd(&out[(int64_t)lTok[rl] * DD + col], lW[rl] * acc0[m][n][r]);
        }
      }
}

extern "C" void kernel_launch(void* const* d_in, const int* in_sizes, int n_in,
                              void* d_out, int out_size, void* d_ws, size_t ws_size,
                              hipStream_t stream) {
  const float* x       = (const float*)d_in[0];
  const float* gw      = (const float*)d_in[1];
  const float* w_gate  = (const float*)d_in[2];
  const float* w_up    = (const float*)d_in[3];
  const float* w_down  = (const float*)d_in[4];
  const float* sw_gate = (const float*)d_in[5];
  const float* sw_up   = (const float*)d_in[6];
  const float* sw_down = (const float*)d_in[7];
  float* out = (float*)d_out;

  char* ws = (char*)d_ws;
  int*   te    = (int*)ws;    ws += NSLOT * 4;
  float* tw    = (float*)ws;  ws += NSLOT * 4;
  int*   cnt   = (int*)ws;    ws += 64 * 4;
  int*   off   = (int*)ws;    ws += 64 * 4;
  int*   eidx  = (int*)ws;    ws += NSLOT * 4;
  float* wslot = (float*)ws;  ws += NSLOT * 4;
  ws = (char*)(((uintptr_t)ws + 255) & ~(uintptr_t)255);
  short* Xb   = (short*)ws;  ws += (size_t)TT * DD * 2;            // 4 MB
  short* Hs   = (short*)ws;  ws += (size_t)TT * FS * 2;            // 11.5 MB
  short* Hr   = (short*)ws;  ws += (size_t)NSLOT * FR * 2;         // 11.5 MB (compact)
  short* wgT  = (short*)ws;  ws += (size_t)NE * FR * DD * 2;       // 23 MB  [E][F][D]
  short* wuT  = (short*)ws;  ws += (size_t)NE * FR * DD * 2;       // 23 MB
  short* wdT  = (short*)ws;  ws += (size_t)NE * DD * FR * 2;       // 23 MB  [E][D][F]
  short* swgT = (short*)ws;  ws += (size_t)FS * DD * 2;            // 5.8 MB [FS][D]
  short* swuT = (short*)ws;  ws += (size_t)FS * DD * 2;            // 5.8 MB
  short* swdT = (short*)ws;  /* [D][FS] 5.8 MB */

  // 1. cast x -> bf16
  cast_kernel<<<dim3((TT * DD) / 1024), dim3(256), 0, stream>>>(x, Xb, TT * DD);
  // 2. gating + dispatch build
  gate_kernel<<<dim3(TT), dim3(64), 0, stream>>>(x, gw, te, tw);
  scatter_kernel<<<dim3(1), dim3(1024), 0, stream>>>(te, tw, cnt, off, eidx, wslot);
  // 3. one-time weight transpose+cast to bf16 [N][K]
  dim3 tb(32, 8);
  tcast_kernel<<<dim3(FR / 32, DD / 32, NE), tb, 0, stream>>>(w_gate, wgT, DD, FR, (int64_t)DD * FR, (int64_t)FR * DD);
  tcast_kernel<<<dim3(FR / 32, DD / 32, NE), tb, 0, stream>>>(w_up,   wuT, DD, FR, (int64_t)DD * FR, (int64_t)FR * DD);
  tcast_kernel<<<dim3(DD / 32, FR / 32, NE), tb, 0, stream>>>(w_down, wdT, FR, DD, (int64_t)FR * DD, (int64_t)DD * FR);
  tcast_kernel<<<dim3(FS / 32, DD / 32, 1),  tb, 0, stream>>>(sw_gate, swgT, DD, FS, 0, 0);
  tcast_kernel<<<dim3(FS / 32, DD / 32, 1),  tb, 0, stream>>>(sw_up,   swuT, DD, FS, 0, 0);
  tcast_kernel<<<dim3(DD / 32, FS / 32, 1),  tb, 0, stream>>>(sw_down, swdT, FS, DD, 0, 0);
  // 4. shared gate/up -> Hs
  moe_gemm<0><<<dim3(FS / 128, TT / 128), dim3(256), 0, stream>>>(
      Xb, DD, swgT, swuT, DD, DD, Hs, FS, nullptr);
  // 5. routed gate/up, sparse (worst-case grid, early exit) -> Hr compact
  gu_sparse<<<dim3(FR / 128, TT / 128, NE), dim3(256), 0, stream>>>(
      Xb, wgT, wuT, Hr, cnt, off, eidx);
  // 6. shared down: out = Hs @ swdT^T (initializes all of out)
  moe_gemm<1><<<dim3(DD / 128, TT / 128), dim3(256), 0, stream>>>(
      Hs, FS, swdT, nullptr, FS, FS, nullptr, 0, out);
  // 7. routed down sparse: out += wslot * (Hr @ wdT^T) (atomicAdd)
  down_sparse<<<dim3(DD / 128, TT / 128, NE), dim3(256), 0, stream>>>(
      Hr, wdT, out, cnt, off, eidx, wslot);
}

// Round 5
// 480.439 us; speedup vs baseline: 1.6724x; 1.0405x over previous
//
#include <hip/hip_runtime.h>
#include <hip/hip_bf16.h>
#include <stdint.h>

#define TT 2048
#define DD 1024
#define NE 8
#define FR 1408
#define FS 2816
#define RSCALE 2.5f
#define NSLOT (TT * 2)
#define TSH 4096  // shorts per 128x32 bf16 tile

typedef __attribute__((ext_vector_type(8))) short bf16x8;
typedef __attribute__((ext_vector_type(4))) float f32x4;

__device__ __forceinline__ short f2bf(float f) {
  uint32_t u = __builtin_bit_cast(uint32_t, f);
  u = (u + 0x7fffu + ((u >> 16) & 1u)) >> 16;
  return (short)(uint16_t)u;
}

// ---------------- cast fp32 -> bf16 (x only) ----------------
__global__ void cast_kernel(const float* __restrict__ in, short* __restrict__ out, int n) {
  int i = (blockIdx.x * blockDim.x + threadIdx.x) * 4;
  if (i >= n) return;
  float4 v = *(const float4*)(in + i);
  short4 o;
  o.x = f2bf(v.x); o.y = f2bf(v.y); o.z = f2bf(v.z); o.w = f2bf(v.w);
  *(short4*)(out + i) = o;
}

// ------- transpose + cast: fp32 [K][N] -> bf16 [N][K]; z-multiplexed over 2 sources -------
__global__ void __launch_bounds__(256) tcastV(const float* __restrict__ in0,
                                              const float* __restrict__ in1,
                                              short* __restrict__ out0, short* __restrict__ out1,
                                              int K, int N, int64_t zin, int64_t zout, int nz) {
  int z = blockIdx.z;
  const float* in;
  short* out;
  if (z < nz) { in = in0 + (int64_t)z * zin; out = out0 + (int64_t)z * zout; }
  else        { int zz = z - nz; in = in1 + (int64_t)zz * zin; out = out1 + (int64_t)zz * zout; }
  __shared__ float tile[32][33];
  const int k0 = blockIdx.y * 32, n0 = blockIdx.x * 32;
  const int tid = threadIdx.x;
  const int lr = tid >> 5, lc = tid & 31;
#pragma unroll
  for (int i = 0; i < 4; ++i)
    tile[lr + i * 8][lc] = in[(int64_t)(k0 + lr + i * 8) * N + n0 + lc];
  __syncthreads();
  const int nl = tid >> 3, kq = (tid & 7) * 4;
  short4 o;
  o.x = f2bf(tile[kq + 0][nl]); o.y = f2bf(tile[kq + 1][nl]);
  o.z = f2bf(tile[kq + 2][nl]); o.w = f2bf(tile[kq + 3][nl]);
  *(short4*)&out[(int64_t)(n0 + nl) * K + k0 + kq] = o;
}

// ------------- gating: softmax over 8, top-2, normalize, scale -> (expert, weight) pairs -------------
__global__ void gate_kernel(const float* __restrict__ x, const float* __restrict__ gw,
                            int* __restrict__ te, float* __restrict__ tw) {
  int t = blockIdx.x;
  int lane = threadIdx.x;  // 64 threads
  const float* xr = x + (size_t)t * DD + lane * 16;
  float4 xv[4];
#pragma unroll
  for (int i = 0; i < 4; ++i) xv[i] = *(const float4*)(xr + i * 4);
  float p[NE];
#pragma unroll
  for (int e = 0; e < NE; ++e) {
    const float* gr = gw + (size_t)e * DD + lane * 16;
    float s = 0.f;
#pragma unroll
    for (int i = 0; i < 4; ++i) {
      float4 g = *(const float4*)(gr + i * 4);
      s += xv[i].x * g.x + xv[i].y * g.y + xv[i].z * g.z + xv[i].w * g.w;
    }
    p[e] = s;
  }
#pragma unroll
  for (int off = 32; off >= 1; off >>= 1) {
#pragma unroll
    for (int e = 0; e < NE; ++e) p[e] += __shfl_xor(p[e], off);
  }
  float mx = p[0];
#pragma unroll
  for (int e = 1; e < NE; ++e) mx = fmaxf(mx, p[e]);
  float s = 0.f, sc[NE];
#pragma unroll
  for (int e = 0; e < NE; ++e) { sc[e] = expf(p[e] - mx); s += sc[e]; }
  float inv = 1.f / s;
#pragma unroll
  for (int e = 0; e < NE; ++e) sc[e] *= inv;
  int e1 = 0;
#pragma unroll
  for (int e = 1; e < NE; ++e) if (sc[e] > sc[e1]) e1 = e;
  int e2 = (e1 == 0) ? 1 : 0;
#pragma unroll
  for (int e = 0; e < NE; ++e) if (e != e1 && sc[e] > sc[e2]) e2 = e;
  float w1 = sc[e1], w2 = sc[e2];
  float k = RSCALE / (w1 + w2 + 1e-20f);
  if (lane == 0) {
    te[t * 2] = e1;     tw[t * 2] = w1 * k;
    te[t * 2 + 1] = e2; tw[t * 2 + 1] = w2 * k;
  }
}

// ------------- build compact per-expert slot lists: cnt/off/eidx/wslot (1 block) -------------
__global__ void __launch_bounds__(1024) scatter_kernel(const int* __restrict__ te,
                                                       const float* __restrict__ tw,
                                                       int* __restrict__ cnt, int* __restrict__ off,
                                                       int* __restrict__ eidx, float* __restrict__ wslot) {
  __shared__ int lcnt[NE], loff[NE], lrun[NE];
  const int tid = threadIdx.x;
  if (tid < NE) lcnt[tid] = 0;
  __syncthreads();
  for (int s = tid; s < NSLOT; s += 1024) atomicAdd(&lcnt[te[s]], 1);
  __syncthreads();
  if (tid == 0) {
    int acc = 0;
    for (int e = 0; e < NE; ++e) { loff[e] = acc; lrun[e] = acc; acc += lcnt[e]; }
  }
  __syncthreads();
  for (int s = tid; s < NSLOT; s += 1024) {
    int e = te[s];
    int p = atomicAdd(&lrun[e], 1);
    eidx[p] = s >> 1;
    wslot[p] = tw[s];
  }
  if (tid < NE) { cnt[tid] = lcnt[tid]; off[tid] = loff[tid]; }
}

// ---- stage a 128x32 bf16 tile (row-major, ld elems) into linear LDS [128][32] ----
__device__ __forceinline__ void stage32(const short* __restrict__ g, int64_t ld,
                                        short* l, int wave, int lane) {
#pragma unroll
  for (int i = 0; i < 2; ++i) {
    int c = i * 256 + wave * 64 + lane;
    __builtin_amdgcn_global_load_lds(
        (const __attribute__((address_space(1))) void*)(g + (int64_t)(c >> 2) * ld + (c & 3) * 8),
        (__attribute__((address_space(3))) void*)(l + (i * 256 + wave * 64) * 8),
        16, 0, 0);
  }
}

// ---------------- dense GEMM (shared expert): 128x128, BK=32, 2-phase dbuf ----------------
// MODE 0: H = silu(A@B0^T)*(A@B1^T) -> bf16 ; MODE 1: O = A@B0^T (fp32 write)
template <int MODE>
__global__ void __launch_bounds__(256) moe_gemm(
    const short* __restrict__ Ab, int lda,
    const short* __restrict__ B0b, const short* __restrict__ B1b, int ldb,
    int K,
    short* __restrict__ Hb, int ldh,
    float* __restrict__ Ob) {
  const int brow = blockIdx.y * 128;
  const int bcol = blockIdx.x * 128;

  __shared__ __align__(16) short lA[2 * TSH];
  __shared__ __align__(16) short lB0[2 * TSH];
  __shared__ __align__(16) short lB1[(MODE == 0) ? 2 * TSH : 8];

  const int tid = threadIdx.x;
  const int lane = tid & 63;
  const int wave = tid >> 6;
  const int wr = wave >> 1, wc = wave & 1;

  f32x4 acc0[4][4];
  f32x4 acc1[(MODE == 0) ? 4 : 1][(MODE == 0) ? 4 : 1];
#pragma unroll
  for (int m = 0; m < 4; ++m)
#pragma unroll
    for (int n = 0; n < 4; ++n) {
      acc0[m][n] = (f32x4){0.f, 0.f, 0.f, 0.f};
      if constexpr (MODE == 0) acc1[m][n] = (f32x4){0.f, 0.f, 0.f, 0.f};
    }

  const short* Abase = Ab + (int64_t)brow * lda;
  const short* B0base = B0b + (int64_t)bcol * ldb;
  const short* B1base = (MODE == 0) ? (B1b + (int64_t)bcol * ldb) : nullptr;

  auto STAGE = [&](int buf, int k0) {
    stage32(Abase + k0, lda, lA + buf * TSH, wave, lane);
    stage32(B0base + k0, ldb, lB0 + buf * TSH, wave, lane);
    if constexpr (MODE == 0) stage32(B1base + k0, ldb, lB1 + buf * TSH, wave, lane);
  };

  STAGE(0, 0);
  __syncthreads();
  int cur = 0;
  for (int k0 = 0; k0 < K; k0 += 32) {
    if (k0 + 32 < K) STAGE(cur ^ 1, k0 + 32);
    const short* A_ = lA + cur * TSH;
    const short* B0_ = lB0 + cur * TSH;
    const short* B1_ = lB1 + cur * TSH;
#pragma unroll
    for (int m = 0; m < 4; ++m) {
      bf16x8 af = *(const bf16x8*)&A_[(wr * 64 + m * 16 + (lane & 15)) * 32 + (lane >> 4) * 8];
#pragma unroll
      for (int n = 0; n < 4; ++n) {
        bf16x8 b0 = *(const bf16x8*)&B0_[(wc * 64 + n * 16 + (lane & 15)) * 32 + (lane >> 4) * 8];
        acc0[m][n] = __builtin_amdgcn_mfma_f32_16x16x32_bf16(af, b0, acc0[m][n], 0, 0, 0);
        if constexpr (MODE == 0) {
          bf16x8 b1 = *(const bf16x8*)&B1_[(wc * 64 + n * 16 + (lane & 15)) * 32 + (lane >> 4) * 8];
          acc1[m][n] = __builtin_amdgcn_mfma_f32_16x16x32_bf16(af, b1, acc1[m][n], 0, 0, 0);
        }
      }
    }
    __syncthreads();
    cur ^= 1;
  }

#pragma unroll
  for (int m = 0; m < 4; ++m)
#pragma unroll
    for (int n = 0; n < 4; ++n)
#pragma unroll
      for (int r = 0; r < 4; ++r) {
        int row = brow + wr * 64 + m * 16 + (lane >> 4) * 4 + r;
        int col = bcol + wc * 64 + n * 16 + (lane & 15);
        float g = acc0[m][n][r];
        if constexpr (MODE == 0) {
          float u = acc1[m][n][r];
          Hb[(int64_t)row * ldh + col] = f2bf(g / (1.f + __expf(-g)) * u);
        } else {
          Ob[(int64_t)row * DD + col] = g;
        }
      }
}

// ---------------- sparse GU: gathered A rows, compact H output, 2-phase dbuf ----------------
__global__ void __launch_bounds__(256) gu_sparse(
    const short* __restrict__ Xb,
    const short* __restrict__ wgT, const short* __restrict__ wuT,
    short* __restrict__ Hr,
    const int* __restrict__ cnt, const int* __restrict__ off,
    const int* __restrict__ eidx) {
  const int z = blockIdx.z;
  const int c = cnt[z];
  const int m0 = blockIdx.y * 128;
  if (m0 >= c) return;
  const int base = off[z];
  const int bcol = blockIdx.x * 128;

  __shared__ __align__(16) short lA[2 * TSH];
  __shared__ __align__(16) short lB0[2 * TSH];
  __shared__ __align__(16) short lB1[2 * TSH];

  const int tid = threadIdx.x;
  const int lane = tid & 63;
  const int wave = tid >> 6;
  const int wr = wave >> 1, wc = wave & 1;

  // per-lane gathered A row pointers (2 chunks of 16B per lane)
  const short* aptr[2];
#pragma unroll
  for (int i = 0; i < 2; ++i) {
    int cl = i * 256 + wave * 64 + lane;
    int r = cl >> 2;
    int sv = m0 + r; if (sv >= c) sv = c - 1;
    aptr[i] = Xb + (int64_t)eidx[base + sv] * DD + (cl & 3) * 8;
  }

  f32x4 acc0[4][4], acc1[4][4];
#pragma unroll
  for (int m = 0; m < 4; ++m)
#pragma unroll
    for (int n = 0; n < 4; ++n) {
      acc0[m][n] = (f32x4){0.f, 0.f, 0.f, 0.f};
      acc1[m][n] = (f32x4){0.f, 0.f, 0.f, 0.f};
    }

  const short* B0base = wgT + (int64_t)z * FR * DD + (int64_t)bcol * DD;
  const short* B1base = wuT + (int64_t)z * FR * DD + (int64_t)bcol * DD;

  auto STAGE = [&](int buf, int k0) {
#pragma unroll
    for (int i = 0; i < 2; ++i)
      __builtin_amdgcn_global_load_lds(
          (const __attribute__((address_space(1))) void*)(aptr[i] + k0),
          (__attribute__((address_space(3))) void*)(lA + buf * TSH + (i * 256 + wave * 64) * 8),
          16, 0, 0);
    stage32(B0base + k0, DD, lB0 + buf * TSH, wave, lane);
    stage32(B1base + k0, DD, lB1 + buf * TSH, wave, lane);
  };

  STAGE(0, 0);
  __syncthreads();
  int cur = 0;
  for (int k0 = 0; k0 < DD; k0 += 32) {
    if (k0 + 32 < DD) STAGE(cur ^ 1, k0 + 32);
    const short* A_ = lA + cur * TSH;
    const short* B0_ = lB0 + cur * TSH;
    const short* B1_ = lB1 + cur * TSH;
#pragma unroll
    for (int m = 0; m < 4; ++m) {
      bf16x8 af = *(const bf16x8*)&A_[(wr * 64 + m * 16 + (lane & 15)) * 32 + (lane >> 4) * 8];
#pragma unroll
      for (int n = 0; n < 4; ++n) {
        bf16x8 b0 = *(const bf16x8*)&B0_[(wc * 64 + n * 16 + (lane & 15)) * 32 + (lane >> 4) * 8];
        acc0[m][n] = __builtin_amdgcn_mfma_f32_16x16x32_bf16(af, b0, acc0[m][n], 0, 0, 0);
        bf16x8 b1 = *(const bf16x8*)&B1_[(wc * 64 + n * 16 + (lane & 15)) * 32 + (lane >> 4) * 8];
        acc1[m][n] = __builtin_amdgcn_mfma_f32_16x16x32_bf16(af, b1, acc1[m][n], 0, 0, 0);
      }
    }
    __syncthreads();
    cur ^= 1;
  }

#pragma unroll
  for (int m = 0; m < 4; ++m)
#pragma unroll
    for (int n = 0; n < 4; ++n)
#pragma unroll
      for (int r = 0; r < 4; ++r) {
        int rl = wr * 64 + m * 16 + (lane >> 4) * 4 + r;
        int sv = m0 + rl;
        if (sv < c) {
          int col = bcol + wc * 64 + n * 16 + (lane & 15);
          float g = acc0[m][n][r], u = acc1[m][n][r];
          Hr[(int64_t)(base + sv) * FR + col] = f2bf(g / (1.f + __expf(-g)) * u);
        }
      }
}

// ---------------- sparse down: compact A rows, scatter-add to out, 2-phase dbuf ----------------
__global__ void __launch_bounds__(256) down_sparse(
    const short* __restrict__ Hr,
    const short* __restrict__ wdT,
    float* __restrict__ out,
    const int* __restrict__ cnt, const int* __restrict__ off,
    const int* __restrict__ eidx, const float* __restrict__ wslot) {
  const int z = blockIdx.z;
  const int c = cnt[z];
  const int m0 = blockIdx.y * 128;
  if (m0 >= c) return;
  const int base = off[z];
  const int bcol = blockIdx.x * 128;

  __shared__ __align__(16) short lA[2 * TSH];
  __shared__ __align__(16) short lB0[2 * TSH];
  __shared__ int lTok[128];
  __shared__ float lW[128];

  const int tid = threadIdx.x;
  const int lane = tid & 63;
  const int wave = tid >> 6;
  const int wr = wave >> 1, wc = wave & 1;

  if (tid < 128) {
    int sv = m0 + tid;
    if (sv < c) { lTok[tid] = eidx[base + sv]; lW[tid] = wslot[base + sv]; }
    else lW[tid] = 0.f;
  }

  f32x4 acc0[4][4];
#pragma unroll
  for (int m = 0; m < 4; ++m)
#pragma unroll
    for (int n = 0; n < 4; ++n) acc0[m][n] = (f32x4){0.f, 0.f, 0.f, 0.f};

  const short* B0base = wdT + (int64_t)z * DD * FR + (int64_t)bcol * FR;

  auto STAGE = [&](int buf, int k0) {
#pragma unroll
    for (int i = 0; i < 2; ++i) {
      int cl = i * 256 + wave * 64 + lane;
      int r = cl >> 2;
      int sv = m0 + r; if (sv >= c) sv = c - 1;
      __builtin_amdgcn_global_load_lds(
          (const __attribute__((address_space(1))) void*)(Hr + (int64_t)(base + sv) * FR + k0 + (cl & 3) * 8),
          (__attribute__((address_space(3))) void*)(lA + buf * TSH + (i * 256 + wave * 64) * 8),
          16, 0, 0);
    }
    stage32(B0base + k0, FR, lB0 + buf * TSH, wave, lane);
  };

  STAGE(0, 0);
  __syncthreads();
  int cur = 0;
  for (int k0 = 0; k0 < FR; k0 += 32) {
    if (k0 + 32 < FR) STAGE(cur ^ 1, k0 + 32);
    const short* A_ = lA + cur * TSH;
    const short* B0_ = lB0 + cur * TSH;
#pragma unroll
    for (int m = 0; m < 4; ++m) {
      bf16x8 af = *(const bf16x8*)&A_[(wr * 64 + m * 16 + (lane & 15)) * 32 + (lane >> 4) * 8];
#pragma unroll
      for (int n = 0; n < 4; ++n) {
        bf16x8 b0 = *(const bf16x8*)&B0_[(wc * 64 + n * 16 + (lane & 15)) * 32 + (lane >> 4) * 8];
        acc0[m][n] = __builtin_amdgcn_mfma_f32_16x16x32_bf16(af, b0, acc0[m][n], 0, 0, 0);
      }
    }
    __syncthreads();
    cur ^= 1;
  }

#pragma unroll
  for (int m = 0; m < 4; ++m)
#pragma unroll
    for (int n = 0; n < 4; ++n)
#pragma unroll
      for (int r = 0; r < 4; ++r) {
        int rl = wr * 64 + m * 16 + (lane >> 4) * 4 + r;
        if (m0 + rl < c) {
          int col = bcol + wc * 64 + n * 16 + (lane & 15);
          atomicAdd(&out[(int64_t)lTok[rl] * DD + col], lW[rl] * acc0[m][n][r]);
        }
      }
}

extern "C" void kernel_launch(void* const* d_in, const int* in_sizes, int n_in,
                              void* d_out, int out_size, void* d_ws, size_t ws_size,
                              hipStream_t stream) {
  const float* x       = (const float*)d_in[0];
  const float* gw      = (const float*)d_in[1];
  const float* w_gate  = (const float*)d_in[2];
  const float* w_up    = (const float*)d_in[3];
  const float* w_down  = (const float*)d_in[4];
  const float* sw_gate = (const float*)d_in[5];
  const float* sw_up   = (const float*)d_in[6];
  const float* sw_down = (const float*)d_in[7];
  float* out = (float*)d_out;

  char* ws = (char*)d_ws;
  int*   te    = (int*)ws;    ws += NSLOT * 4;
  float* tw    = (float*)ws;  ws += NSLOT * 4;
  int*   cnt   = (int*)ws;    ws += 64 * 4;
  int*   off   = (int*)ws;    ws += 64 * 4;
  int*   eidx  = (int*)ws;    ws += NSLOT * 4;
  float* wslot = (float*)ws;  ws += NSLOT * 4;
  ws = (char*)(((uintptr_t)ws + 255) & ~(uintptr_t)255);
  short* Xb   = (short*)ws;  ws += (size_t)TT * DD * 2;            // 4 MB
  short* Hs   = (short*)ws;  ws += (size_t)TT * FS * 2;            // 11.5 MB
  short* Hr   = (short*)ws;  ws += (size_t)NSLOT * FR * 2;         // 11.5 MB (compact)
  short* wgT  = (short*)ws;  ws += (size_t)NE * FR * DD * 2;       // 23 MB  [E][F][D]
  short* wuT  = (short*)ws;  ws += (size_t)NE * FR * DD * 2;       // 23 MB
  short* wdT  = (short*)ws;  ws += (size_t)NE * DD * FR * 2;       // 23 MB  [E][D][F]
  short* swgT = (short*)ws;  ws += (size_t)FS * DD * 2;            // 5.8 MB [FS][D]
  short* swuT = (short*)ws;  ws += (size_t)FS * DD * 2;            // 5.8 MB
  short* swdT = (short*)ws;  /* [D][FS] 5.8 MB */

  // 1. cast x -> bf16
  cast_kernel<<<dim3((TT * DD) / 1024), dim3(256), 0, stream>>>(x, Xb, TT * DD);
  // 2. gating + dispatch build
  gate_kernel<<<dim3(TT), dim3(64), 0, stream>>>(x, gw, te, tw);
  scatter_kernel<<<dim3(1), dim3(1024), 0, stream>>>(te, tw, cnt, off, eidx, wslot);
  // 3. one-time weight transpose+cast to bf16 [N][K] (4 merged launches, short4 stores)
  tcastV<<<dim3(FR / 32, DD / 32, 2 * NE), dim3(256), 0, stream>>>(
      w_gate, w_up, wgT, wuT, DD, FR, (int64_t)DD * FR, (int64_t)FR * DD, NE);
  tcastV<<<dim3(DD / 32, FR / 32, NE), dim3(256), 0, stream>>>(
      w_down, w_down, wdT, wdT, FR, DD, (int64_t)FR * DD, (int64_t)DD * FR, NE);
  tcastV<<<dim3(FS / 32, DD / 32, 2), dim3(256), 0, stream>>>(
      sw_gate, sw_up, swgT, swuT, DD, FS, 0, 0, 1);
  tcastV<<<dim3(DD / 32, FS / 32, 1), dim3(256), 0, stream>>>(
      sw_down, sw_down, swdT, swdT, FS, DD, 0, 0, 1);
  // 4. shared gate/up -> Hs
  moe_gemm<0><<<dim3(FS / 128, TT / 128), dim3(256), 0, stream>>>(
      Xb, DD, swgT, swuT, DD, DD, Hs, FS, nullptr);
  // 5. routed gate/up, sparse (worst-case grid, early exit) -> Hr compact
  gu_sparse<<<dim3(FR / 128, TT / 128, NE), dim3(256), 0, stream>>>(
      Xb, wgT, wuT, Hr, cnt, off, eidx);
  // 6. shared down: out = Hs @ swdT^T (initializes all of out)
  moe_gemm<1><<<dim3(DD / 128, TT / 128), dim3(256), 0, stream>>>(
      Hs, FS, swdT, nullptr, FS, FS, nullptr, 0, out);
  // 7. routed down sparse: out += wslot * (Hr @ wdT^T) (atomicAdd)
  down_sparse<<<dim3(DD / 128, TT / 128, NE), dim3(256), 0, stream>>>(
      Hr, wdT, out, cnt, off, eidx, wslot);
}

// Round 6
// 434.355 us; speedup vs baseline: 1.8498x; 1.1061x over previous
//
#include <hip/hip_runtime.h>
#include <hip/hip_bf16.h>
#include <stdint.h>

#define TT 2048
#define DD 1024
#define NE 8
#define FR 1408
#define FS 2816
#define RSCALE 2.5f
#define NSLOT (TT * 2)
#define NVSLOT (NSLOT + 2 * TT)   // routed compact + 2 shared virtual experts
#define NZ (NE + 2)               // 8 routed + 2 shared halves
#define TSH 4096                  // shorts per 128x32 bf16 tile

typedef __attribute__((ext_vector_type(8))) short bf16x8;
typedef __attribute__((ext_vector_type(4))) float f32x4;

__device__ __forceinline__ short f2bf(float f) {
  uint32_t u = __builtin_bit_cast(uint32_t, f);
  u = (u + 0x7fffu + ((u >> 16) & 1u)) >> 16;
  return (short)(uint16_t)u;
}

// ---------------- cast fp32 -> bf16 (x only) ----------------
__global__ void cast_kernel(const float* __restrict__ in, short* __restrict__ out, int n) {
  int i = (blockIdx.x * blockDim.x + threadIdx.x) * 4;
  if (i >= n) return;
  float4 v = *(const float4*)(in + i);
  short4 o;
  o.x = f2bf(v.x); o.y = f2bf(v.y); o.z = f2bf(v.z); o.w = f2bf(v.w);
  *(short4*)(out + i) = o;
}

// ------- transpose + cast: fp32 [K][N] -> bf16 [N][K]; z-multiplexed over 2 sources -------
__global__ void __launch_bounds__(256) tcastV(const float* __restrict__ in0,
                                              const float* __restrict__ in1,
                                              short* __restrict__ out0, short* __restrict__ out1,
                                              int K, int N, int64_t zin, int64_t zout, int nz) {
  int z = blockIdx.z;
  const float* in;
  short* out;
  if (z < nz) { in = in0 + (int64_t)z * zin; out = out0 + (int64_t)z * zout; }
  else        { int zz = z - nz; in = in1 + (int64_t)zz * zin; out = out1 + (int64_t)zz * zout; }
  __shared__ float tile[32][33];
  const int k0 = blockIdx.y * 32, n0 = blockIdx.x * 32;
  const int tid = threadIdx.x;
  const int lr = tid >> 5, lc = tid & 31;
#pragma unroll
  for (int i = 0; i < 4; ++i)
    tile[lr + i * 8][lc] = in[(int64_t)(k0 + lr + i * 8) * N + n0 + lc];
  __syncthreads();
  const int nl = tid >> 3, kq = (tid & 7) * 4;
  short4 o;
  o.x = f2bf(tile[kq + 0][nl]); o.y = f2bf(tile[kq + 1][nl]);
  o.z = f2bf(tile[kq + 2][nl]); o.w = f2bf(tile[kq + 3][nl]);
  *(short4*)&out[(int64_t)(n0 + nl) * K + k0 + kq] = o;
}

// ------------- gating: softmax over 8, top-2, normalize, scale -> (expert, weight) pairs -------------
__global__ void gate_kernel(const float* __restrict__ x, const float* __restrict__ gw,
                            int* __restrict__ te, float* __restrict__ tw) {
  int t = blockIdx.x;
  int lane = threadIdx.x;  // 64 threads
  const float* xr = x + (size_t)t * DD + lane * 16;
  float4 xv[4];
#pragma unroll
  for (int i = 0; i < 4; ++i) xv[i] = *(const float4*)(xr + i * 4);
  float p[NE];
#pragma unroll
  for (int e = 0; e < NE; ++e) {
    const float* gr = gw + (size_t)e * DD + lane * 16;
    float s = 0.f;
#pragma unroll
    for (int i = 0; i < 4; ++i) {
      float4 g = *(const float4*)(gr + i * 4);
      s += xv[i].x * g.x + xv[i].y * g.y + xv[i].z * g.z + xv[i].w * g.w;
    }
    p[e] = s;
  }
#pragma unroll
  for (int off = 32; off >= 1; off >>= 1) {
#pragma unroll
    for (int e = 0; e < NE; ++e) p[e] += __shfl_xor(p[e], off);
  }
  float mx = p[0];
#pragma unroll
  for (int e = 1; e < NE; ++e) mx = fmaxf(mx, p[e]);
  float s = 0.f, sc[NE];
#pragma unroll
  for (int e = 0; e < NE; ++e) { sc[e] = expf(p[e] - mx); s += sc[e]; }
  float inv = 1.f / s;
#pragma unroll
  for (int e = 0; e < NE; ++e) sc[e] *= inv;
  int e1 = 0;
#pragma unroll
  for (int e = 1; e < NE; ++e) if (sc[e] > sc[e1]) e1 = e;
  int e2 = (e1 == 0) ? 1 : 0;
#pragma unroll
  for (int e = 0; e < NE; ++e) if (e != e1 && sc[e] > sc[e2]) e2 = e;
  float w1 = sc[e1], w2 = sc[e2];
  float k = RSCALE / (w1 + w2 + 1e-20f);
  if (lane == 0) {
    te[t * 2] = e1;     tw[t * 2] = w1 * k;
    te[t * 2 + 1] = e2; tw[t * 2 + 1] = w2 * k;
  }
}

// ------------- build compact per-expert slot lists (+2 shared virtual experts) -------------
__global__ void __launch_bounds__(1024) scatter_kernel(const int* __restrict__ te,
                                                       const float* __restrict__ tw,
                                                       int* __restrict__ cnt, int* __restrict__ off,
                                                       int* __restrict__ eidx, float* __restrict__ wslot) {
  __shared__ int lcnt[NE], loff[NE], lrun[NE];
  const int tid = threadIdx.x;
  if (tid < NE) lcnt[tid] = 0;
  __syncthreads();
  for (int s = tid; s < NSLOT; s += 1024) atomicAdd(&lcnt[te[s]], 1);
  __syncthreads();
  if (tid == 0) {
    int acc = 0;
    for (int e = 0; e < NE; ++e) { loff[e] = acc; lrun[e] = acc; acc += lcnt[e]; }
  }
  __syncthreads();
  for (int s = tid; s < NSLOT; s += 1024) {
    int e = te[s];
    int p = atomicAdd(&lrun[e], 1);
    eidx[p] = s >> 1;
    wslot[p] = tw[s];
  }
  // shared virtual experts: identity slot lists, weight 1.0
  for (int t = tid; t < TT; t += 1024) {
    eidx[NSLOT + t] = t;       wslot[NSLOT + t] = 1.0f;
    eidx[NSLOT + TT + t] = t;  wslot[NSLOT + TT + t] = 1.0f;
  }
  if (tid < NE) { cnt[tid] = lcnt[tid]; off[tid] = loff[tid]; }
  if (tid == NE)     { cnt[NE] = TT;     off[NE] = NSLOT; }
  if (tid == NE + 1) { cnt[NE + 1] = TT; off[NE + 1] = NSLOT + TT; }
}

// ---- stage a 128x32 bf16 tile (row-major, ld elems) into linear LDS [128][32] ----
__device__ __forceinline__ void stage32(const short* __restrict__ g, int64_t ld,
                                        short* l, int wave, int lane) {
#pragma unroll
  for (int i = 0; i < 2; ++i) {
    int c = i * 256 + wave * 64 + lane;
    __builtin_amdgcn_global_load_lds(
        (const __attribute__((address_space(1))) void*)(g + (int64_t)(c >> 2) * ld + (c & 3) * 8),
        (__attribute__((address_space(3))) void*)(l + (i * 256 + wave * 64) * 8),
        16, 0, 0);
  }
}

// ---------------- unified GU: 10 virtual experts, gathered A rows, compact H out ----------------
__global__ void __launch_bounds__(256) gu_all(
    const short* __restrict__ Xb,
    const short* __restrict__ wgT, const short* __restrict__ wuT,
    const short* __restrict__ swgT, const short* __restrict__ swuT,
    short* __restrict__ Hall,
    const int* __restrict__ cnt, const int* __restrict__ off,
    const int* __restrict__ eidx) {
  const int z = blockIdx.z;
  const int c = cnt[z];
  const int m0 = blockIdx.y * 128;
  if (m0 >= c) return;
  const int base = off[z];
  const int bcol = blockIdx.x * 128;

  __shared__ __align__(16) short lA[2 * TSH];
  __shared__ __align__(16) short lB0[2 * TSH];
  __shared__ __align__(16) short lB1[2 * TSH];

  const int tid = threadIdx.x;
  const int lane = tid & 63;
  const int wave = tid >> 6;
  const int wr = wave >> 1, wc = wave & 1;

  const short *B0base, *B1base;
  if (z < NE) {
    B0base = wgT + ((int64_t)z * FR + bcol) * DD;
    B1base = wuT + ((int64_t)z * FR + bcol) * DD;
  } else {
    int h = z - NE;
    B0base = swgT + ((int64_t)h * FR + bcol) * DD;
    B1base = swuT + ((int64_t)h * FR + bcol) * DD;
  }

  // per-lane gathered A row pointers (2 chunks of 16B per lane)
  const short* aptr[2];
#pragma unroll
  for (int i = 0; i < 2; ++i) {
    int cl = i * 256 + wave * 64 + lane;
    int r = cl >> 2;
    int sv = m0 + r; if (sv >= c) sv = c - 1;
    aptr[i] = Xb + (int64_t)eidx[base + sv] * DD + (cl & 3) * 8;
  }

  f32x4 acc0[4][4], acc1[4][4];
#pragma unroll
  for (int m = 0; m < 4; ++m)
#pragma unroll
    for (int n = 0; n < 4; ++n) {
      acc0[m][n] = (f32x4){0.f, 0.f, 0.f, 0.f};
      acc1[m][n] = (f32x4){0.f, 0.f, 0.f, 0.f};
    }

  auto STAGE = [&](int buf, int k0) {
#pragma unroll
    for (int i = 0; i < 2; ++i)
      __builtin_amdgcn_global_load_lds(
          (const __attribute__((address_space(1))) void*)(aptr[i] + k0),
          (__attribute__((address_space(3))) void*)(lA + buf * TSH + (i * 256 + wave * 64) * 8),
          16, 0, 0);
    stage32(B0base + k0, DD, lB0 + buf * TSH, wave, lane);
    stage32(B1base + k0, DD, lB1 + buf * TSH, wave, lane);
  };

  STAGE(0, 0);
  __syncthreads();
  int cur = 0;
  for (int k0 = 0; k0 < DD; k0 += 32) {
    if (k0 + 32 < DD) STAGE(cur ^ 1, k0 + 32);
    const short* A_ = lA + cur * TSH;
    const short* B0_ = lB0 + cur * TSH;
    const short* B1_ = lB1 + cur * TSH;
#pragma unroll
    for (int m = 0; m < 4; ++m) {
      bf16x8 af = *(const bf16x8*)&A_[(wr * 64 + m * 16 + (lane & 15)) * 32 + (lane >> 4) * 8];
#pragma unroll
      for (int n = 0; n < 4; ++n) {
        bf16x8 b0 = *(const bf16x8*)&B0_[(wc * 64 + n * 16 + (lane & 15)) * 32 + (lane >> 4) * 8];
        acc0[m][n] = __builtin_amdgcn_mfma_f32_16x16x32_bf16(af, b0, acc0[m][n], 0, 0, 0);
        bf16x8 b1 = *(const bf16x8*)&B1_[(wc * 64 + n * 16 + (lane & 15)) * 32 + (lane >> 4) * 8];
        acc1[m][n] = __builtin_amdgcn_mfma_f32_16x16x32_bf16(af, b1, acc1[m][n], 0, 0, 0);
      }
    }
    __syncthreads();
    cur ^= 1;
  }

#pragma unroll
  for (int m = 0; m < 4; ++m)
#pragma unroll
    for (int n = 0; n < 4; ++n)
#pragma unroll
      for (int r = 0; r < 4; ++r) {
        int rl = wr * 64 + m * 16 + (lane >> 4) * 4 + r;
        int sv = m0 + rl;
        if (sv < c) {
          int col = bcol + wc * 64 + n * 16 + (lane & 15);
          float g = acc0[m][n][r], u = acc1[m][n][r];
          Hall[(int64_t)(base + sv) * FR + col] = f2bf(g / (1.f + __expf(-g)) * u);
        }
      }
}

// ---------------- unified down: 10 virtual experts, K=1408, scatter-add to out ----------------
__global__ void __launch_bounds__(256) down_all(
    const short* __restrict__ Hall,
    const short* __restrict__ wdT, const short* __restrict__ swdT,
    float* __restrict__ out,
    const int* __restrict__ cnt, const int* __restrict__ off,
    const int* __restrict__ eidx, const float* __restrict__ wslot) {
  const int z = blockIdx.z;
  const int c = cnt[z];
  const int m0 = blockIdx.y * 128;
  if (m0 >= c) return;
  const int base = off[z];
  const int bcol = blockIdx.x * 128;

  __shared__ __align__(16) short lA[2 * TSH];
  __shared__ __align__(16) short lB0[2 * TSH];
  __shared__ int lTok[128];
  __shared__ float lW[128];

  const int tid = threadIdx.x;
  const int lane = tid & 63;
  const int wave = tid >> 6;
  const int wr = wave >> 1, wc = wave & 1;

  const short* B0base;
  int64_t ldb;
  if (z < NE) { B0base = wdT + ((int64_t)z * DD + bcol) * FR; ldb = FR; }
  else        { B0base = swdT + (int64_t)bcol * FS + (int64_t)(z - NE) * FR; ldb = FS; }

  if (tid < 128) {
    int sv = m0 + tid;
    if (sv < c) { lTok[tid] = eidx[base + sv]; lW[tid] = wslot[base + sv]; }
    else lW[tid] = 0.f;
  }

  f32x4 acc0[4][4];
#pragma unroll
  for (int m = 0; m < 4; ++m)
#pragma unroll
    for (int n = 0; n < 4; ++n) acc0[m][n] = (f32x4){0.f, 0.f, 0.f, 0.f};

  auto STAGE = [&](int buf, int k0) {
#pragma unroll
    for (int i = 0; i < 2; ++i) {
      int cl = i * 256 + wave * 64 + lane;
      int r = cl >> 2;
      int sv = m0 + r; if (sv >= c) sv = c - 1;
      __builtin_amdgcn_global_load_lds(
          (const __attribute__((address_space(1))) void*)(Hall + (int64_t)(base + sv) * FR + k0 + (cl & 3) * 8),
          (__attribute__((address_space(3))) void*)(lA + buf * TSH + (i * 256 + wave * 64) * 8),
          16, 0, 0);
    }
    stage32(B0base + k0, ldb, lB0 + buf * TSH, wave, lane);
  };

  STAGE(0, 0);
  __syncthreads();
  int cur = 0;
  for (int k0 = 0; k0 < FR; k0 += 32) {
    if (k0 + 32 < FR) STAGE(cur ^ 1, k0 + 32);
    const short* A_ = lA + cur * TSH;
    const short* B0_ = lB0 + cur * TSH;
#pragma unroll
    for (int m = 0; m < 4; ++m) {
      bf16x8 af = *(const bf16x8*)&A_[(wr * 64 + m * 16 + (lane & 15)) * 32 + (lane >> 4) * 8];
#pragma unroll
      for (int n = 0; n < 4; ++n) {
        bf16x8 b0 = *(const bf16x8*)&B0_[(wc * 64 + n * 16 + (lane & 15)) * 32 + (lane >> 4) * 8];
        acc0[m][n] = __builtin_amdgcn_mfma_f32_16x16x32_bf16(af, b0, acc0[m][n], 0, 0, 0);
      }
    }
    __syncthreads();
    cur ^= 1;
  }

#pragma unroll
  for (int m = 0; m < 4; ++m)
#pragma unroll
    for (int n = 0; n < 4; ++n)
#pragma unroll
      for (int r = 0; r < 4; ++r) {
        int rl = wr * 64 + m * 16 + (lane >> 4) * 4 + r;
        if (m0 + rl < c) {
          int col = bcol + wc * 64 + n * 16 + (lane & 15);
          atomicAdd(&out[(int64_t)lTok[rl] * DD + col], lW[rl] * acc0[m][n][r]);
        }
      }
}

extern "C" void kernel_launch(void* const* d_in, const int* in_sizes, int n_in,
                              void* d_out, int out_size, void* d_ws, size_t ws_size,
                              hipStream_t stream) {
  const float* x       = (const float*)d_in[0];
  const float* gw      = (const float*)d_in[1];
  const float* w_gate  = (const float*)d_in[2];
  const float* w_up    = (const float*)d_in[3];
  const float* w_down  = (const float*)d_in[4];
  const float* sw_gate = (const float*)d_in[5];
  const float* sw_up   = (const float*)d_in[6];
  const float* sw_down = (const float*)d_in[7];
  float* out = (float*)d_out;

  char* ws = (char*)d_ws;
  int*   te    = (int*)ws;    ws += NSLOT * 4;
  float* tw    = (float*)ws;  ws += NSLOT * 4;
  int*   cnt   = (int*)ws;    ws += 64 * 4;
  int*   off   = (int*)ws;    ws += 64 * 4;
  int*   eidx  = (int*)ws;    ws += NVSLOT * 4;
  float* wslot = (float*)ws;  ws += NVSLOT * 4;
  ws = (char*)(((uintptr_t)ws + 255) & ~(uintptr_t)255);
  short* Xb   = (short*)ws;  ws += (size_t)TT * DD * 2;            // 4 MB
  short* Hall = (short*)ws;  ws += (size_t)NVSLOT * FR * 2;        // 23 MB (compact + shared)
  short* wgT  = (short*)ws;  ws += (size_t)NE * FR * DD * 2;       // 23 MB  [E][F][D]
  short* wuT  = (short*)ws;  ws += (size_t)NE * FR * DD * 2;       // 23 MB
  short* wdT  = (short*)ws;  ws += (size_t)NE * DD * FR * 2;       // 23 MB  [E][D][F]
  short* swgT = (short*)ws;  ws += (size_t)FS * DD * 2;            // 5.8 MB [FS][D]
  short* swuT = (short*)ws;  ws += (size_t)FS * DD * 2;            // 5.8 MB
  short* swdT = (short*)ws;  /* [D][FS] 5.8 MB */

  // 1. cast x -> bf16
  cast_kernel<<<dim3((TT * DD) / 1024), dim3(256), 0, stream>>>(x, Xb, TT * DD);
  // 2. gating + dispatch build (incl. shared virtual experts)
  gate_kernel<<<dim3(TT), dim3(64), 0, stream>>>(x, gw, te, tw);
  scatter_kernel<<<dim3(1), dim3(1024), 0, stream>>>(te, tw, cnt, off, eidx, wslot);
  // 3. one-time weight transpose+cast to bf16 [N][K]
  tcastV<<<dim3(FR / 32, DD / 32, 2 * NE), dim3(256), 0, stream>>>(
      w_gate, w_up, wgT, wuT, DD, FR, (int64_t)DD * FR, (int64_t)FR * DD, NE);
  tcastV<<<dim3(DD / 32, FR / 32, NE), dim3(256), 0, stream>>>(
      w_down, w_down, wdT, wdT, FR, DD, (int64_t)FR * DD, (int64_t)DD * FR, NE);
  tcastV<<<dim3(FS / 32, DD / 32, 2), dim3(256), 0, stream>>>(
      sw_gate, sw_up, swgT, swuT, DD, FS, 0, 0, 1);
  tcastV<<<dim3(DD / 32, FS / 32, 1), dim3(256), 0, stream>>>(
      sw_down, sw_down, swdT, swdT, FS, DD, 0, 0, 1);
  // 4. zero out (all contributions accumulate via atomicAdd)
  hipMemsetAsync(out, 0, (size_t)TT * DD * 4, stream);
  // 5. unified gate/up over 10 virtual experts -> Hall
  gu_all<<<dim3(FR / 128, NSLOT / 128, NZ), dim3(256), 0, stream>>>(
      Xb, wgT, wuT, swgT, swuT, Hall, cnt, off, eidx);
  // 6. unified down over 10 virtual experts: out += wslot * (Hall @ B^T)
  down_all<<<dim3(DD / 128, NSLOT / 128, NZ), dim3(256), 0, stream>>>(
      Hall, wdT, swdT, out, cnt, off, eidx, wslot);
}